// Round 8
// baseline (217.208 us; speedup 1.0000x reference)
//
#include <hip/hip_runtime.h>
#include <hip/hip_bf16.h>
#include <stdint.h>

// Problem constants (B=2, N=M=2048, C=1024, H=16, hd=64)
#define SEQ   2048
#define CH    1024
#define NH    16
#define HD    64
#define NUMEL (2 * NH * SEQ * HD)   // 4,194,304 elems per split-half

typedef short bf8 __attribute__((ext_vector_type(8)));   // 8 bf16 (4 VGPRs)
typedef short bf4 __attribute__((ext_vector_type(4)));   // 4 bf16 (2 VGPRs)
typedef float f4  __attribute__((ext_vector_type(4)));   // MFMA C/D frag
typedef unsigned short u16;

#define GAS(p) ((const __attribute__((address_space(1))) void*)(p))
#define LAS(p) ((__attribute__((address_space(3))) void*)(p))

__device__ __forceinline__ u16 f2bf(float f) {
  uint32_t u = __float_as_uint(f);
  u += 0x7fffu + ((u >> 16) & 1u);   // RNE
  return (u16)(u >> 16);
}

__device__ __forceinline__ float bf2f(u16 v) {
  return __uint_as_float(((uint32_t)v) << 16);
}

// packed f32x2 -> bf16x2 (v_cvt_pk_bf16_f32 on gfx950)
__device__ __forceinline__ uint32_t pk2bf(float a, float b) {
  float2 f; f.x = a; f.y = b;
  __hip_bfloat162 h = __float22bfloat162_rn(f);
  union { __hip_bfloat162 h; uint32_t u; } cv; cv.h = h;
  return cv.u;
}

__device__ __forceinline__ f4 MFMA32(bf8 a, bf8 b, f4 c) {
  return __builtin_amdgcn_mfma_f32_16x16x32_bf16(a, b, c, 0, 0, 0);
}

// K=16 MFMA: A-layout [m=l16][k=q*4+reg] == C/D layout of a 16x16 frag.
__device__ __forceinline__ f4 MFMA16(bf4 a, bf4 b, f4 c) {
#if __has_builtin(__builtin_amdgcn_mfma_f32_16x16x16_bf16)
  return __builtin_amdgcn_mfma_f32_16x16x16_bf16(a, b, c, 0, 0, 0);
#elif __has_builtin(__builtin_amdgcn_mfma_f32_16x16x16bf16_1k)
  return __builtin_amdgcn_mfma_f32_16x16x16bf16_1k(a, b, c, 0, 0, 0);
#else
  f4 d = c;
  asm volatile("v_mfma_f32_16x16x16_bf16 %0, %1, %2, %0"
               : "+v"(d) : "v"(a), "v"(b));
  return d;
#endif
}

// -------- prep: fp32->bf16 activations + transpose-convert all weights ------
__global__ void prep(const float* __restrict__ ref, u16* __restrict__ refb,
                     const float* __restrict__ tgt, u16* __restrict__ tgtb,
                     const float* __restrict__ Wq, u16* __restrict__ Wqt,
                     const float* __restrict__ Wkv, u16* __restrict__ Wkvt,
                     const float* __restrict__ Wp, u16* __restrict__ Wpt) {
  __shared__ float tile[32][33];
  int blk = blockIdx.x;
  int t = threadIdx.x;
  if (blk < 8192) {
    const float* in; u16* out;
    if (blk < 4096) { in = ref; out = refb; } else { in = tgt; out = tgtb; blk -= 4096; }
    int i = (blk * 256 + t) * 4;
    float4 f = *reinterpret_cast<const float4*>(in + i);
    ushort4 o;
    o.x = f2bf(f.x); o.y = f2bf(f.y); o.z = f2bf(f.z); o.w = f2bf(f.w);
    *reinterpret_cast<ushort4*>(out + i) = o;
    return;
  }
  blk -= 8192;
  int x = blk & 127, by = blk >> 7;
  const float* in; u16* out; int N;
  if (x < 32)       { in = Wq;  out = Wqt;  N = CH;     }
  else if (x < 96)  { in = Wkv; out = Wkvt; N = 2 * CH; x -= 32; }
  else              { in = Wp;  out = Wpt;  N = CH;     x -= 96; }
  const int K = CH;
  int bn = x * 32, bk = by * 32;
  int tx = t & 31, ty = t >> 5;
  #pragma unroll
  for (int i = ty; i < 32; i += 8)
    tile[i][tx] = in[(size_t)(bk + i) * N + bn + tx];
  __syncthreads();
  #pragma unroll
  for (int i = ty; i < 32; i += 8)
    out[(size_t)(bn + i) * K + bk + tx] = f2bf(tile[tx][i]);
}

// ---------------- fused Q-proj + KV-proj GEMM, dbuf, 3 blocks/CU -------------
// 1D grid 768: blk = n_idx*32 + m_idx (same-B blocks consecutive -> L2 reuse)
__global__ __launch_bounds__(256, 3)
void gemm_qkv(const u16* __restrict__ tgtb, const u16* __restrict__ refb,
              const u16* __restrict__ Wqt, const u16* __restrict__ Wkvt,
              u16* __restrict__ qb, u16* __restrict__ karr, u16* __restrict__ varr)
{
  __shared__ __align__(16) u16 As[2][4096];
  __shared__ __align__(16) u16 Bs[2][4096];
  const int tid = threadIdx.x;
  const int lane = tid & 63, wave = tid >> 6;
  const int l16 = lane & 15, q = lane >> 4;
  const int blk = blockIdx.x;
  const int n_idx = blk >> 5, m_idx = blk & 31;
  const bool isQ = n_idx >= 16;
  const u16* A  = isQ ? tgtb : refb;
  const u16* Bt = isQ ? Wqt : Wkvt;
  const int n0 = (isQ ? (n_idx - 16) : n_idx) * 128;
  const int m0 = m_idx * 128;
  const int wm = (wave >> 1) * 64, wn = (wave & 1) * 64;
  const int Kdim = CH;
  const int c = tid, c2 = tid + 256;
  const int ar = c >> 2, ac = (c & 3) << 3, ar2 = c2 >> 2, ac2 = (c2 & 3) << 3;

  f4 acc[4][4] = {};

  #define STAGE_G(buf, k0)                                                      \
    { __builtin_amdgcn_global_load_lds(                                         \
          GAS(&A[(size_t)(m0 + ar) * Kdim + (k0) + ac]),                        \
          LAS(&As[buf][c << 3]), 16, 0, 0);                                     \
      __builtin_amdgcn_global_load_lds(                                         \
          GAS(&A[(size_t)(m0 + ar2) * Kdim + (k0) + ac2]),                      \
          LAS(&As[buf][c2 << 3]), 16, 0, 0);                                    \
      __builtin_amdgcn_global_load_lds(                                         \
          GAS(&Bt[(size_t)(n0 + ar) * Kdim + (k0) + ac]),                       \
          LAS(&Bs[buf][c << 3]), 16, 0, 0);                                     \
      __builtin_amdgcn_global_load_lds(                                         \
          GAS(&Bt[(size_t)(n0 + ar2) * Kdim + (k0) + ac2]),                     \
          LAS(&Bs[buf][c2 << 3]), 16, 0, 0); }

  STAGE_G(0, 0);
  for (int kk = 0; kk < 32; ++kk) {
    __syncthreads();
    if (kk < 31) STAGE_G((kk + 1) & 1, (kk + 1) * 32);
    const u16* as = As[kk & 1];
    const u16* bs = Bs[kk & 1];
    bf8 a[4], b[4];
    #pragma unroll
    for (int i = 0; i < 4; ++i)
      a[i] = *reinterpret_cast<const bf8*>(&as[(wm + i * 16 + l16) * 32 + q * 8]);
    #pragma unroll
    for (int j = 0; j < 4; ++j)
      b[j] = *reinterpret_cast<const bf8*>(&bs[(wn + j * 16 + l16) * 32 + q * 8]);
    #pragma unroll
    for (int i = 0; i < 4; ++i)
      #pragma unroll
      for (int j = 0; j < 4; ++j)
        acc[i][j] = MFMA32(a[i], b[j], acc[i][j]);
  }
  #undef STAGE_G

  // epilogue — C/D layout: col = lane&15, row = (lane>>4)*4 + reg   [m89/m91]
  #pragma unroll
  for (int i = 0; i < 4; ++i) {
    const int mbase = m0 + wm + i * 16 + q * 4;
    const int b = mbase >> 11, ns0 = mbase & (SEQ - 1);
    #pragma unroll
    for (int j = 0; j < 4; ++j) {
      const int n = n0 + wn + j * 16 + l16;
      if (isQ) {
        int h = n >> 6, d = n & 63;
        #pragma unroll
        for (int r = 0; r < 4; ++r)
          qb[(size_t)((b * NH + h) * SEQ + ns0 + r) * HD + d] =
              f2bf(acc[i][j][r] * 0.1803368801f);
      } else if (n < CH) {  // K -> a-frag order (scalar: r stride = 16B)
        int h = n >> 6, d = n & 63;
        size_t base = (size_t)(b * NH + h) * SEQ * HD;
        int off = (((ns0 >> 4) * 2 + (d >> 5)) * 4 + ((d >> 3) & 3)) * 128
                  + (d & 7);
        #pragma unroll
        for (int r = 0; r < 4; ++r)
          karr[base + off + ((ns0 + r) & 15) * 8] = f2bf(acc[i][j][r]);
      } else {  // V -> paired b-frag order (b128 loads in attn): 8B store
        int c2v = n - CH, h = c2v >> 6, d = c2v & 63;
        size_t base = (size_t)(b * NH + h) * SEQ * HD;
        int off = (((ns0 >> 4) * 2 + (d >> 5)) * 4 + ((ns0 >> 2) & 3)) * 128
                  + (d & 15) * 8 + ((d >> 4) & 1) * 4;
        ushort4 st;
        st.x = f2bf(acc[i][j][0]); st.y = f2bf(acc[i][j][1]);
        st.z = f2bf(acc[i][j][2]); st.w = f2bf(acc[i][j][3]);
        *reinterpret_cast<ushort4*>(&varr[base + off]) = st;
      }
    }
  }
}

// ------- out-proj GEMM: 64x128 tile, 1D grid 512 (same-B consecutive) -------
__global__ __launch_bounds__(256, 2)
void gemm_proj(const u16* __restrict__ A, const u16* __restrict__ Bt,
               float* __restrict__ fo, const float* __restrict__ bias)
{
  __shared__ __align__(16) u16 As[2][2048];   // 64 x 32
  __shared__ __align__(16) u16 Bs[2][4096];   // 128 x 32
  const int tid = threadIdx.x;
  const int lane = tid & 63, wave = tid >> 6;
  const int l16 = lane & 15, q = lane >> 4;
  const int blk = blockIdx.x;
  const int m0 = (blk & 63) * 64, n0 = (blk >> 6) * 128;
  const int wm = (wave >> 1) * 32, wn = (wave & 1) * 64;
  const int Kdim = CH;
  const int c = tid, c2 = tid + 256;
  const int ar = c >> 2, ac = (c & 3) << 3, ar2 = c2 >> 2, ac2 = (c2 & 3) << 3;
  const int aar = c >> 2, aac = (c & 3) << 3;   // 64 rows x 4 chunks = 256

  f4 acc[2][4] = {};

  #define STAGE_P(buf, k0)                                                      \
    { __builtin_amdgcn_global_load_lds(                                         \
          GAS(&A[(size_t)(m0 + aar) * Kdim + (k0) + aac]),                      \
          LAS(&As[buf][c << 3]), 16, 0, 0);                                     \
      __builtin_amdgcn_global_load_lds(                                         \
          GAS(&Bt[(size_t)(n0 + ar) * Kdim + (k0) + ac]),                       \
          LAS(&Bs[buf][c << 3]), 16, 0, 0);                                     \
      __builtin_amdgcn_global_load_lds(                                         \
          GAS(&Bt[(size_t)(n0 + ar2) * Kdim + (k0) + ac2]),                     \
          LAS(&Bs[buf][c2 << 3]), 16, 0, 0); }

  STAGE_P(0, 0);
  for (int kk = 0; kk < 32; ++kk) {
    __syncthreads();
    if (kk < 31) STAGE_P((kk + 1) & 1, (kk + 1) * 32);
    const u16* as = As[kk & 1];
    const u16* bs = Bs[kk & 1];
    bf8 a[2], b[4];
    #pragma unroll
    for (int i = 0; i < 2; ++i)
      a[i] = *reinterpret_cast<const bf8*>(&as[(wm + i * 16 + l16) * 32 + q * 8]);
    #pragma unroll
    for (int j = 0; j < 4; ++j)
      b[j] = *reinterpret_cast<const bf8*>(&bs[(wn + j * 16 + l16) * 32 + q * 8]);
    #pragma unroll
    for (int i = 0; i < 2; ++i)
      #pragma unroll
      for (int j = 0; j < 4; ++j)
        acc[i][j] = MFMA32(a[i], b[j], acc[i][j]);
  }
  #undef STAGE_P

  #pragma unroll
  for (int i = 0; i < 2; ++i) {
    const int mbase = m0 + wm + i * 16 + q * 4;
    #pragma unroll
    for (int j = 0; j < 4; ++j) {
      const int n = n0 + wn + j * 16 + l16;
      #pragma unroll
      for (int r = 0; r < 4; ++r)
        fo[(size_t)(mbase + r) * CH + n] = acc[i][j][r] + bias[n];
    }
  }
}

// -------- flash attention, KV-split x2, fixed-max, single-buffered ----------
// grid (16, 32, 2), 512 thr. Each block does half the key range; partial
// numerator (bf16) and denominator (f32) written to workspace; combine merges.
__global__ __launch_bounds__(512, 8)
void attn(const u16* __restrict__ Q, const u16* __restrict__ Karr,
          const u16* __restrict__ Varr, u16* __restrict__ num,
          float* __restrict__ den)
{
  __shared__ __align__(16) u16 Ks[8192];   // 16 KB
  __shared__ __align__(16) u16 Vs[8192];   // 16 KB
  const int tid = threadIdx.x;
  const int lane = tid & 63;
  const int l16 = lane & 15, q = lane >> 4;
  const int bh = blockIdx.y;
  const int m0 = blockIdx.x * 128;
  const int sp = blockIdx.z;               // split half
  const int wm = (tid >> 6) * 16;

  const u16* Qb = Q    + (size_t)bh * SEQ * HD;
  const u16* Kb = Karr + (size_t)bh * SEQ * HD;
  const u16* Vb = Varr + (size_t)bh * SEQ * HD;

  bf8 qf[2];
  #pragma unroll
  for (int ks = 0; ks < 2; ++ks)
    qf[ks] = *reinterpret_cast<const bf8*>(
        &Qb[(size_t)(m0 + wm + l16) * HD + ks * 32 + q * 8]);

  const short one_bf = 0x3F80;
  const bf4 ones = {one_bf, one_bf, one_bf, one_bf};

  f4 o[4] = {};
  f4 ds = {};

  const int t0 = sp * 8;                   // 8 tiles of 128 keys per half
  for (int t = 0; t < 8; ++t) {
    const int tt = t0 + t;
    __syncthreads();                       // LDS reuse fence
    {
      const u16* kg = Kb + (size_t)tt * 8192;
      const u16* vg = Vb + (size_t)tt * 8192;
      #pragma unroll
      for (int s = 0; s < 2; ++s) {
        int cc = tid + s * 512;
        __builtin_amdgcn_global_load_lds(GAS(kg + cc * 8), LAS(&Ks[cc * 8]), 16, 0, 0);
        __builtin_amdgcn_global_load_lds(GAS(vg + cc * 8), LAS(&Vs[cc * 8]), 16, 0, 0);
      }
    }
    __syncthreads();

    bf4 pa[8];
    #pragma unroll
    for (int j = 0; j < 8; ++j) {
      bf8 kf0 = *reinterpret_cast<const bf8*>(&Ks[((j * 2 + 0) * 4 + q) * 128 + l16 * 8]);
      bf8 kf1 = *reinterpret_cast<const bf8*>(&Ks[((j * 2 + 1) * 4 + q) * 128 + l16 * 8]);
      f4 z = {};
      z = MFMA32(kf0, qf[0], z);
      z = MFMA32(kf1, qf[1], z);
      union { bf4 v; uint32_t u[2]; } w;
      w.u[0] = pk2bf(exp2f(z[0]), exp2f(z[1]));
      w.u[1] = pk2bf(exp2f(z[2]), exp2f(z[3]));
      pa[j] = w.v;
    }

    #pragma unroll
    for (int j = 0; j < 8; ++j) {
      ds = MFMA16(pa[j], ones, ds);
      #pragma unroll
      for (int dh = 0; dh < 2; ++dh) {
        bf8 vv = *reinterpret_cast<const bf8*>(&Vs[((j * 2 + dh) * 4 + q) * 128 + l16 * 8]);
        bf4 v0 = __builtin_shufflevector(vv, vv, 0, 1, 2, 3);
        bf4 v1 = __builtin_shufflevector(vv, vv, 4, 5, 6, 7);
        o[dh * 2 + 0] = MFMA16(pa[j], v0, o[dh * 2 + 0]);
        o[dh * 2 + 1] = MFMA16(pa[j], v1, o[dh * 2 + 1]);
      }
    }
  }

  // write partials: num[sp][bh][m][d] bf16, den[sp][bh][m] f32
  u16* nh = num + (size_t)sp * NUMEL;
  float* dh_ = den + (size_t)sp * (2 * NH * SEQ);
  #pragma unroll
  for (int r = 0; r < 4; ++r) {
    int m = m0 + wm + q * 4 + r;
    if (l16 == 0) dh_[bh * SEQ + m] = ds[r];
    #pragma unroll
    for (int dt = 0; dt < 4; ++dt)
      nh[((size_t)bh * SEQ + m) * HD + dt * 16 + l16] = f2bf(o[dt][r]);
  }
}

// -------- combine: xb = (num0+num1)/(den0+den1), write bf16 [B*M, C] --------
__global__ void combine(const u16* __restrict__ num, const float* __restrict__ den,
                        u16* __restrict__ xb) {
  int idx = (blockIdx.x * 256 + threadIdx.x) * 4;   // over NUMEL
  int bh = idx >> 17;                               // SEQ*HD = 2^17
  int rem = idx & (SEQ * HD - 1);
  int m = rem >> 6, d = rem & 63;
  ushort4 a = *reinterpret_cast<const ushort4*>(num + idx);
  ushort4 b4 = *reinterpret_cast<const ushort4*>(num + NUMEL + idx);
  float dsum = den[bh * SEQ + m] + den[2 * NH * SEQ + bh * SEQ + m];
  float inv = 1.0f / dsum;
  int b = bh >> 4, h = bh & (NH - 1);
  ushort4 o;
  o.x = f2bf((bf2f(a.x) + bf2f(b4.x)) * inv);
  o.y = f2bf((bf2f(a.y) + bf2f(b4.y)) * inv);
  o.z = f2bf((bf2f(a.z) + bf2f(b4.z)) * inv);
  o.w = f2bf((bf2f(a.w) + bf2f(b4.w)) * inv);
  *reinterpret_cast<ushort4*>(&xb[(size_t)(b * SEQ + m) * CH + h * HD + d]) = o;
}

// ---------------- launch ----------------
extern "C" void kernel_launch(void* const* d_in, const int* in_sizes, int n_in,
                              void* d_out, int out_size, void* d_ws, size_t ws_size,
                              hipStream_t stream) {
  const float* ref   = (const float*)d_in[0];   // [B,N,C]
  const float* tgt   = (const float*)d_in[1];   // [B,M,C]
  const float* Wq    = (const float*)d_in[2];   // [C,C]
  const float* Wkv   = (const float*)d_in[3];   // [C,2C]
  const float* Wproj = (const float*)d_in[4];   // [C,C]
  const float* bproj = (const float*)d_in[5];   // [C]
  float* out = (float*)d_out;                   // [B,M,C] fp32

  // workspace layout (bytes): total 56 MiB; refb/tgtb/Wqt are dead after
  // gemm_qkv and reused for attention partials.
  char* ws = (char*)d_ws;
  u16* refb = (u16*)(ws);                 // 8 MiB  -> num[0] after qkv
  u16* tgtb = (u16*)(ws + (8  << 20));    // 8 MiB  -> num[1] after qkv
  u16* Wqt  = (u16*)(ws + (16 << 20));    // 2 MiB  -> den after qkv
  u16* Wkvt = (u16*)(ws + (18 << 20));    // 4 MiB
  u16* Wpt  = (u16*)(ws + (22 << 20));    // 2 MiB  (live until gemm_proj)
  u16* qb   = (u16*)(ws + (24 << 20));    // 8 MiB  [B,H,M,hd] (pre-scaled)
  u16* karr = (u16*)(ws + (32 << 20));    // 8 MiB  a-frag order
  u16* varr = (u16*)(ws + (40 << 20));    // 8 MiB  paired b-frag order
  u16* xb   = (u16*)(ws + (48 << 20));    // 8 MiB  [B*M, C]
  u16* nbuf  = refb;                      // 16 MiB (both halves)
  float* dbuf = (float*)Wqt;              // 512 KiB

  prep<<<12288, 256, 0, stream>>>(ref, refb, tgt, tgtb, Wq, Wqt, Wkv, Wkvt, Wproj, Wpt);

  gemm_qkv<<<768, 256, 0, stream>>>(tgtb, refb, Wqt, Wkvt, qb, karr, varr);

  attn<<<dim3(16, 32, 2), 512, 0, stream>>>(qb, karr, varr, nbuf, dbuf);

  combine<<<4096, 256, 0, stream>>>(nbuf, dbuf, xb);

  gemm_proj<<<512, 256, 0, stream>>>(xb, Wpt, out, bproj);
}